// Round 5
// baseline (88.412 us; speedup 1.0000x reference)
//
#include <hip/hip_runtime.h>
#include <stdint.h>

#define B_    4
#define S_    4096
#define D_    64
#define QBLK  64
#define KVBLK 64
#define NT    (S_ / KVBLK)
#define NELEM (B_ * S_ * D_)   // 1048576 per tensor
#define BS_   (B_ * S_)        // 16384

typedef __attribute__((ext_vector_type(8))) short bf16x8;
typedef __attribute__((ext_vector_type(4))) short bf16x4;
typedef __attribute__((ext_vector_type(4))) float f32x4;
typedef __attribute__((ext_vector_type(4))) int   i32x4;
typedef __attribute__((ext_vector_type(4))) unsigned u32x4;
typedef __attribute__((ext_vector_type(4))) _Float16 f16x4;

#define MFMA(a, b, c) __builtin_amdgcn_mfma_f32_16x16x32_bf16(a, b, c, 0, 0, 0)
#define VMWAIT(n) asm volatile("s_waitcnt vmcnt(" #n ")" ::: "memory")
#define BARRIER() do { asm volatile("" ::: "memory"); __builtin_amdgcn_s_barrier(); asm volatile("" ::: "memory"); } while (0)
// Read-retirement fence before releasing LDS writers (rule #18).
#define LGKM_FENCE() do { asm volatile("s_waitcnt lgkmcnt(0)" ::: "memory"); __builtin_amdgcn_sched_barrier(0); } while (0)

__device__ __forceinline__ short f2bf(float x) {
    unsigned u = __builtin_bit_cast(unsigned, x);
    u += 0x7FFFu + ((u >> 16) & 1u);
    return (short)(u >> 16);
}

__device__ __forceinline__ unsigned cvtpk(float lo, float hi) {
    unsigned r;
    asm("v_cvt_pk_bf16_f32 %0, %1, %2" : "=v"(r) : "v"(lo), "v"(hi));
    return r;
}

__device__ __forceinline__ void async16(const short* g, short* l) {
    __builtin_amdgcn_global_load_lds(
        (const __attribute__((address_space(1))) unsigned int*)g,
        (__attribute__((address_space(3))) unsigned int*)l, 16, 0, 0);
}

// ---------------- merged pre-pass ----------------
// blocks [0,4096): f32->bf16 cvt of q_re(x.125), q_im(x.125), k_re, k_im
// blocks [4096,4608): V transpose f32[B][S][D] -> bf16 vT[B][D][S] with
//   key-permuted 64-blocks: pos p (0..63) holds key
//   key(p) = 32*(p>>5) + 4*((p&31)>>3) + 16*((p>>2)&1) + (p&3)
//   so that PV's A-fragment (keys 32hf+4h+16e+r) is one contiguous b128.
__global__ __launch_bounds__(256)
void prepass_kernel(const float* __restrict__ q_re, const float* __restrict__ q_im,
                    const float* __restrict__ k_re, const float* __restrict__ k_im,
                    const float* __restrict__ v_re, const float* __restrict__ v_im,
                    short* __restrict__ ws) {
    const int bidx = blockIdx.x;
    const int tid  = threadIdx.x;
    if (bidx < 4096) {
        const int idx = bidx * 256 + tid;               // f32x4 slots
        const int tn  = idx >> 18;
        const int e4  = idx & ((1 << 18) - 1);
        const float* s = (tn == 0 ? q_re : tn == 1 ? q_im : tn == 2 ? k_re : k_im)
                         + (size_t)e4 * 4;
        const float sc = (tn < 2) ? 0.125f : 1.0f;      // fold softmax scale into Q
        f32x4 x = *(const f32x4*)s;
        bf16x4 v;
#pragma unroll
        for (int c = 0; c < 4; ++c) v[c] = f2bf(x[c] * sc);
        *(bf16x4*)(ws + (size_t)tn * NELEM + (size_t)e4 * 4) = v;
    } else {
        __shared__ short tile[64][72];
        const int tb   = bidx - 4096;       // 0..511
        const int sb   = tb & 63;
        const int b    = (tb >> 6) & 3;
        const int comp = tb >> 8;
        const float* src = comp ? v_im : v_re;
        short* dst = ws + (size_t)(4 + comp) * NELEM;
#pragma unroll
        for (int i = 0; i < 4; ++i) {
            const int slot = i * 256 + tid;
            const int s  = slot >> 4;
            const int d4 = slot & 15;
            f32x4 x = *(const f32x4*)(src + (((size_t)b * S_) + sb * 64 + s) * D_ + d4 * 4);
#pragma unroll
            for (int c = 0; c < 4; ++c) tile[d4 * 4 + c][s] = f2bf(x[c]);
        }
        __syncthreads();
#pragma unroll
        for (int i = 0; i < 2; ++i) {
            const int slot = i * 256 + tid;
            const int d = slot >> 3;
            const int m = slot & 7;               // pos-group (8 consecutive pos)
            const int a = m >> 2, hh = m & 3;     // key = 32a + 4hh + 16(j>>2) + (j&3)
            bf16x8 v;
#pragma unroll
            for (int j = 0; j < 8; ++j)
                v[j] = tile[d][a * 32 + hh * 4 + ((j >> 2) << 4) + (j & 3)];
            *(bf16x8*)(dst + ((size_t)b * 64 + d) * S_ + sb * 64 + m * 8) = v;
        }
    }
}

// ---------------- main flash kernel: pipelined single-buffer staging ----------------
template<int SPLIT, typename OT>
__global__ __launch_bounds__(256, 4)
void cv_attn_main(const short* __restrict__ wsb,
                  float* __restrict__ out,
                  OT* __restrict__ opart,
                  float* __restrict__ ml)
{
    __shared__ __align__(16) short smem[4 * KVBLK * D_];   // 32 KiB: kr|ki|vr|vi
    short* kr_s = smem;
    short* ki_s = smem + 4096;
    short* vr_s = smem + 8192;
    short* vi_s = smem + 12288;

    const int tid  = threadIdx.x;
    const int lane = tid & 63;
    const int wv   = tid >> 6;
    const int l15  = lane & 15;
    const int h    = lane >> 4;

    int bid = blockIdx.x;
    const int nwg = B_ * 64 * SPLIT;
    bid = (bid & 7) * (nwg >> 3) + (bid >> 3);
    const int qb = bid & 63;
    const int sp = (bid >> 6) % SPLIT;
    const int b  = bid / (64 * SPLIT);

    const short* qr  = wsb;
    const short* qi  = wsb + (size_t)NELEM;
    const short* kr  = wsb + 2 * (size_t)NELEM;
    const short* ki  = wsb + 3 * (size_t)NELEM;
    const short* vrT = wsb + 4 * (size_t)NELEM;
    const short* viT = wsb + 5 * (size_t)NELEM;

    // Unified LDS read bases (shorts). unit(dh or hf, h) = (grp*4+h) ^ (l15&7);
    // grp=1 is grp=0 XOR'd by 4. All 4 arrays + c/dc steps are immediates off these.
    short* kb0 = smem + l15 * 64 + ((h ^ (l15 & 7)) << 3);
    short* kb1 = smem + l15 * 64 + (((h ^ 4) ^ (l15 & 7)) << 3);

    // persistent Q fragments (already scaled by 0.125)
    const int qrow = qb * QBLK + wv * 16 + l15;
    const size_t qoff = ((size_t)b * S_ + qrow) * D_;
    bf16x8 fqr[2], fqi[2], fqn[2];
#pragma unroll
    for (int dh = 0; dh < 2; ++dh) {
        fqr[dh] = *(const bf16x8*)(qr + qoff + dh * 32 + h * 8);
        fqi[dh] = *(const bf16x8*)(qi + qoff + dh * 32 + h * 8);
        i32x4 n = __builtin_bit_cast(i32x4, fqi[dh]) ^ (int)0x80008000;
        fqn[dh] = __builtin_bit_cast(bf16x8, n);
    }

    f32x4 o_re[4], o_im[4];
#pragma unroll
    for (int i = 0; i < 4; ++i) {
        o_re[i] = (f32x4){0.f, 0.f, 0.f, 0.f};
        o_im[i] = (f32x4){0.f, 0.f, 0.f, 0.f};
    }
    float m_run = -1e30f, l_run = 0.f;
    const float L2E = 1.44269504088896f;

    const int r8   = lane >> 3;
    const int u16l = lane & 7;
    constexpr int TPB = NT / SPLIT;

    auto stageK = [&](int t) {
        const int kb = (sp * TPB + t) * KVBLK;
#pragma unroll
        for (int i = 0; i < 2; ++i) {
            const int row   = wv * 16 + i * 8 + r8;
            const int lbase = (wv * 16 + i * 8) * 64;
            const int swz   = (u16l ^ (row & 7)) << 3;
            const size_t koff = ((size_t)b * S_ + kb + row) * 64 + swz;
            async16(kr + koff, kr_s + lbase);
            async16(ki + koff, ki_s + lbase);
        }
    };
    auto stageV = [&](int t) {
        const int kb = (sp * TPB + t) * KVBLK;
#pragma unroll
        for (int i = 0; i < 2; ++i) {
            const int row   = wv * 16 + i * 8 + r8;
            const int lbase = (wv * 16 + i * 8) * 64;
            const int swz   = (u16l ^ (row & 7)) << 3;
            const size_t voff = ((size_t)b * 64 + row) * S_ + kb + swz;
            async16(vrT + voff, vr_s + lbase);
            async16(viT + voff, vi_s + lbase);
        }
    };

    stageK(0);
    stageV(0);

    for (int tt = 0; tt < TPB; ++tt) {
        const bool last = (tt == TPB - 1);

        // ---- K(tt) landed? (own 4 K ops oldest; 4 V ops may fly) ----
        VMWAIT(4);
        BARRIER();

        // ---- scores: S^T = K * Q^T (all reads immediate-offset b128) ----
        f32x4 s_re[4], s_im[4];
#pragma unroll
        for (int c = 0; c < 4; ++c) {
            s_re[c] = (f32x4){0.f, 0.f, 0.f, 0.f};
            s_im[c] = (f32x4){0.f, 0.f, 0.f, 0.f};
        }
        __builtin_amdgcn_s_setprio(1);
#pragma unroll
        for (int c = 0; c < 4; ++c) {
            bf16x8 fkr0 = *(const bf16x8*)(kb0 + c * 1024);
            bf16x8 fkr1 = *(const bf16x8*)(kb1 + c * 1024);
            bf16x8 fki0 = *(const bf16x8*)(kb0 + 4096 + c * 1024);
            bf16x8 fki1 = *(const bf16x8*)(kb1 + 4096 + c * 1024);
            s_re[c] = MFMA(fkr0, fqr[0], s_re[c]);
            s_re[c] = MFMA(fkr1, fqr[1], s_re[c]);
            s_re[c] = MFMA(fki0, fqn[0], s_re[c]);
            s_re[c] = MFMA(fki1, fqn[1], s_re[c]);
            s_im[c] = MFMA(fki0, fqr[0], s_im[c]);
            s_im[c] = MFMA(fki1, fqr[1], s_im[c]);
            s_im[c] = MFMA(fkr0, fqi[0], s_im[c]);
            s_im[c] = MFMA(fkr1, fqi[1], s_im[c]);
        }
        __builtin_amdgcn_s_setprio(0);

        LGKM_FENCE();                 // my K ds_reads retired before writers released
        BARRIER();
        if (!last) stageK(tt + 1);    // K(tt+1) flies under softmax+PV

        // ---- magnitude (s_re <- mg) ----
#pragma unroll
        for (int c = 0; c < 4; ++c) {
            f32x4 g = s_re[c] * s_re[c] + s_im[c] * s_im[c];
#pragma unroll
            for (int r = 0; r < 4; ++r) s_re[c][r] = __builtin_amdgcn_sqrtf(g[r]);
        }
        float tmax = s_re[0][0];
#pragma unroll
        for (int c = 0; c < 4; ++c)
#pragma unroll
            for (int r = 0; r < 4; ++r) tmax = fmaxf(tmax, s_re[c][r]);
        tmax = fmaxf(tmax, __shfl_xor(tmax, 16));
        tmax = fmaxf(tmax, __shfl_xor(tmax, 32));

        // ---- defer-max (T13) ----
        if (__any(tmax > m_run + 8.0f)) {
            const float m_new = fmaxf(m_run, tmax);
            const float alpha = __builtin_amdgcn_exp2f((m_run - m_new) * L2E);
            l_run *= alpha;
#pragma unroll
            for (int i = 0; i < 4; ++i) { o_re[i] *= alpha; o_im[i] *= alpha; }
            m_run = m_new;
        }
        const float nm = -m_run * L2E;

        // ---- p = exp2(mg*L2E + nm)  (s_im <- p) ----
#pragma unroll
        for (int c = 0; c < 4; ++c)
#pragma unroll
            for (int r = 0; r < 4; ++r)
                s_im[c][r] = __builtin_amdgcn_exp2f(__builtin_fmaf(s_re[c][r], L2E, nm));
        f32x4 ps = s_im[0] + s_im[1] + s_im[2] + s_im[3];
        l_run += (ps[0] + ps[1]) + (ps[2] + ps[3]);

        // ---- pack P via v_cvt_pk_bf16_f32 ----
        bf16x8 pb[2];
#pragma unroll
        for (int hf = 0; hf < 2; ++hf) {
            u32x4 w;
            w[0] = cvtpk(s_im[hf * 2][0],     s_im[hf * 2][1]);
            w[1] = cvtpk(s_im[hf * 2][2],     s_im[hf * 2][3]);
            w[2] = cvtpk(s_im[hf * 2 + 1][0], s_im[hf * 2 + 1][1]);
            w[3] = cvtpk(s_im[hf * 2 + 1][2], s_im[hf * 2 + 1][3]);
            pb[hf] = __builtin_bit_cast(bf16x8, w);
        }

        // ---- V(tt) landed? (K(tt+1)'s 4 ops may fly) ----
        if (!last) { VMWAIT(4); } else { VMWAIT(0); }
        BARRIER();

        // ---- PV: O^T += V^T * W^T (permuted-key layout: single b128 per frag) ----
        __builtin_amdgcn_s_setprio(1);
#pragma unroll
        for (int hf = 0; hf < 2; ++hf) {
            const short* kbh = hf ? kb1 : kb0;
#pragma unroll
            for (int dc = 0; dc < 4; ++dc) {
                bf16x8 av = *(const bf16x8*)(kbh + 8192  + dc * 1024);
                bf16x8 ai = *(const bf16x8*)(kbh + 12288 + dc * 1024);
                o_re[dc] = MFMA(av, pb[hf], o_re[dc]);
                o_im[dc] = MFMA(ai, pb[hf], o_im[dc]);
            }
        }
        __builtin_amdgcn_s_setprio(0);

        LGKM_FENCE();                 // my V ds_reads retired before writers released
        BARRIER();
        if (!last) stageV(tt + 1);    // V(tt+1) flies under next QK^T+softmax
    }

    // ---------------- epilogue ----------------
    float lt = l_run;
    lt += __shfl_xor(lt, 16);
    lt += __shfl_xor(lt, 32);
    const float inv = (SPLIT == 1) ? (1.0f / lt) : 1.0f;

    float* ol = (float*)smem;   // 64 x 65 f32 overlay

    OT* dst_re;
    OT* dst_im;
    if constexpr (SPLIT == 1) {
        dst_re = (OT*)out + ((size_t)b * S_ + qb * QBLK) * D_;
        dst_im = dst_re + (size_t)NELEM;
    } else {
        const size_t qo = ((size_t)b * S_ + qb * QBLK) * D_;
        dst_re = opart + ((size_t)sp * 2 + 0) * NELEM + qo;
        dst_im = opart + ((size_t)sp * 2 + 1) * NELEM + qo;
    }

    auto store_comp = [&](const f32x4 (&oc)[4], OT* og) {
        __syncthreads();
#pragma unroll
        for (int dc = 0; dc < 4; ++dc)
#pragma unroll
            for (int r = 0; r < 4; ++r)
                ol[(wv * 16 + l15) * 65 + dc * 16 + h * 4 + r] = oc[dc][r] * inv;
        __syncthreads();
#pragma unroll
        for (int i = 0; i < 4; ++i) {
            const int slot = i * 256 + tid;
            const int row  = slot >> 4;
            const int c4   = slot & 15;
            f32x4 v;
#pragma unroll
            for (int j = 0; j < 4; ++j) v[j] = ol[row * 65 + c4 * 4 + j];
            if constexpr (sizeof(OT) == 4) {
                *(f32x4*)((float*)og + (size_t)row * D_ + c4 * 4) = v;
            } else {
                f16x4 hv;
#pragma unroll
                for (int j = 0; j < 4; ++j) hv[j] = (_Float16)v[j];
                *(f16x4*)((_Float16*)og + (size_t)row * D_ + c4 * 4) = hv;
            }
        }
    };
    store_comp(o_re, dst_re);
    store_comp(o_im, dst_im);

    if constexpr (SPLIT > 1) {
        if (lane < 16) {
            const int row = qb * QBLK + wv * 16 + lane;
            const size_t mo = ((size_t)sp * BS_ + (size_t)b * S_ + row) * 2;
            ml[mo]     = m_run;
            ml[mo + 1] = lt;
        }
    }
}

// ---------------- combine partial KV-splits ----------------
template<int SPLIT, typename OT>
__global__ __launch_bounds__(256)
void cv_attn_combine(const OT* __restrict__ opart, const float* __restrict__ ml,
                     float* __restrict__ out) {
    const int idx  = blockIdx.x * 256 + threadIdx.x;
    const int d4   = idx & 15;
    const int rest = idx >> 4;
    const int row  = rest & (BS_ - 1);
    const int comp = rest >> 14;
    float ms[SPLIT], ls[SPLIT];
    float M = -1e30f;
#pragma unroll
    for (int s = 0; s < SPLIT; ++s) {
        ms[s] = ml[((size_t)s * BS_ + row) * 2];
        ls[s] = ml[((size_t)s * BS_ + row) * 2 + 1];
        M = fmaxf(M, ms[s]);
    }
    float L = 0.f;
    f32x4 acc = (f32x4){0.f, 0.f, 0.f, 0.f};
#pragma unroll
    for (int s = 0; s < SPLIT; ++s) {
        const float w = __builtin_amdgcn_exp2f((ms[s] - M) * 1.44269504088896f);
        L += ls[s] * w;
        const OT* op = opart + ((size_t)(s * 2 + comp)) * NELEM + (size_t)row * D_ + d4 * 4;
        f32x4 o;
        if constexpr (sizeof(OT) == 4) {
            o = *(const f32x4*)op;
        } else {
            f16x4 hv = *(const f16x4*)op;
#pragma unroll
            for (int j = 0; j < 4; ++j) o[j] = (float)hv[j];
        }
        acc += o * w;
    }
    const float invL = 1.0f / L;
    acc *= invL;
    *(f32x4*)(out + (size_t)comp * NELEM + (size_t)row * D_ + d4 * 4) = acc;
}

// ---------------- legacy fallback (f32 direct, self-contained) ----------------
__global__ __launch_bounds__(256, 1)
void cv_attn_legacy(const float* __restrict__ q_re, const float* __restrict__ q_im,
                    const float* __restrict__ k_re, const float* __restrict__ k_im,
                    const float* __restrict__ v_re, const float* __restrict__ v_im,
                    float* __restrict__ out)
{
    __shared__ __align__(16) short smem[4 * KVBLK * D_];
    short* kr_s = smem;
    short* ki_s = smem + 4096;
    short* vr_s = smem + 8192;
    short* vi_s = smem + 12288;

    const int tid  = threadIdx.x;
    const int lane = tid & 63;
    const int wv   = tid >> 6;
    const int l15  = lane & 15;
    const int h    = lane >> 4;

    const int b  = blockIdx.x >> 6;
    const int qb = blockIdx.x & 63;
    const size_t boff = (size_t)b * S_ * D_;

    const int qrow = qb * QBLK + wv * 16 + l15;
    const float* qrp = q_re + boff + (size_t)qrow * D_;
    const float* qip = q_im + boff + (size_t)qrow * D_;
    bf16x8 fqr[2], fqi[2], fqn[2];
#pragma unroll
    for (int dh = 0; dh < 2; ++dh) {
        const int d0 = dh * 32 + h * 8;
        f32x4 a0 = *(const f32x4*)(qrp + d0);
        f32x4 a1 = *(const f32x4*)(qrp + d0 + 4);
        f32x4 b0 = *(const f32x4*)(qip + d0);
        f32x4 b1 = *(const f32x4*)(qip + d0 + 4);
#pragma unroll
        for (int j = 0; j < 4; ++j) {
            fqr[dh][j] = f2bf(a0[j]); fqr[dh][j + 4] = f2bf(a1[j]);
            fqi[dh][j] = f2bf(b0[j]); fqi[dh][j + 4] = f2bf(b1[j]);
            fqn[dh][j] = f2bf(-b0[j]); fqn[dh][j + 4] = f2bf(-b1[j]);
        }
    }

    f32x4 o_re[4], o_im[4];
#pragma unroll
    for (int i = 0; i < 4; ++i) {
        o_re[i] = (f32x4){0.f, 0.f, 0.f, 0.f};
        o_im[i] = (f32x4){0.f, 0.f, 0.f, 0.f};
    }
    float m_run = -1e30f, l_run = 0.f;
    const float SC = 0.125f * 1.44269504088896f;

    for (int t = 0; t < NT; ++t) {
        const int kb = t * KVBLK;
#pragma unroll
        for (int a = 0; a < 2; ++a) {
            const float* src = (a ? k_im : k_re) + boff;
            short* dst = a ? ki_s : kr_s;
#pragma unroll
            for (int i = 0; i < 2; ++i) {
                const int slot = i * 256 + tid;
                const int row  = slot >> 3;
                const int cb   = slot & 7;
                const float* p = src + (size_t)(kb + row) * D_ + cb * 8;
                f32x4 x0 = *(const f32x4*)p;
                f32x4 x1 = *(const f32x4*)(p + 4);
                bf16x8 v;
#pragma unroll
                for (int j = 0; j < 4; ++j) { v[j] = f2bf(x0[j]); v[j + 4] = f2bf(x1[j]); }
                *(bf16x8*)(dst + row * 64 + ((cb ^ (row & 7)) << 3)) = v;
            }
        }
#pragma unroll
        for (int a = 0; a < 2; ++a) {
            const float* src = (a ? v_im : v_re) + boff;
            short* dst = a ? vi_s : vr_s;
#pragma unroll
            for (int i = 0; i < 4; ++i) {
                const int slot = i * 256 + tid;
                const int k  = slot >> 4;
                const int d4 = slot & 15;
                f32x4 x = *(const f32x4*)(src + (size_t)(kb + k) * D_ + d4 * 4);
#pragma unroll
                for (int c = 0; c < 4; ++c) {
                    const int d = d4 * 4 + c;
                    dst[d * 64 + (((k >> 2) ^ (d & 15)) << 2) + (k & 3)] = f2bf(x[c]);
                }
            }
        }
        __syncthreads();

        f32x4 s_re[4], s_im[4];
#pragma unroll
        for (int c = 0; c < 4; ++c) {
            s_re[c] = (f32x4){0.f, 0.f, 0.f, 0.f};
            s_im[c] = (f32x4){0.f, 0.f, 0.f, 0.f};
        }
#pragma unroll
        for (int c = 0; c < 4; ++c) {
            const int krow = c * 16 + l15;
#pragma unroll
            for (int dh = 0; dh < 2; ++dh) {
                const int u = ((dh * 4 + h) ^ (krow & 7)) << 3;
                bf16x8 fkr = *(const bf16x8*)(kr_s + krow * 64 + u);
                bf16x8 fki = *(const bf16x8*)(ki_s + krow * 64 + u);
                s_re[c] = MFMA(fkr, fqr[dh], s_re[c]);
                s_re[c] = MFMA(fki, fqn[dh], s_re[c]);
                s_im[c] = MFMA(fki, fqr[dh], s_im[c]);
                s_im[c] = MFMA(fkr, fqi[dh], s_im[c]);
            }
        }

        float pv[4][4];
        float tmax = 0.f;
#pragma unroll
        for (int c = 0; c < 4; ++c)
#pragma unroll
            for (int r = 0; r < 4; ++r) {
                const float re = s_re[c][r], im = s_im[c][r];
                const float mg = __builtin_amdgcn_sqrtf(re * re + im * im) * SC;
                pv[c][r] = mg;
                tmax = fmaxf(tmax, mg);
            }
        tmax = fmaxf(tmax, __shfl_xor(tmax, 16));
        tmax = fmaxf(tmax, __shfl_xor(tmax, 32));
        const float m_new = fmaxf(m_run, tmax);
        const float alpha = __builtin_amdgcn_exp2f(m_run - m_new);
        m_run = m_new;
        float psum = 0.f;
#pragma unroll
        for (int c = 0; c < 4; ++c)
#pragma unroll
            for (int r = 0; r < 4; ++r) {
                const float e = __builtin_amdgcn_exp2f(pv[c][r] - m_new);
                pv[c][r] = e;
                psum += e;
            }
        l_run = l_run * alpha + psum;
#pragma unroll
        for (int i = 0; i < 4; ++i) { o_re[i] *= alpha; o_im[i] *= alpha; }

        bf16x8 pb[2];
#pragma unroll
        for (int hf = 0; hf < 2; ++hf)
#pragma unroll
            for (int j = 0; j < 4; ++j) {
                pb[hf][j]     = f2bf(pv[hf * 2][j]);
                pb[hf][j + 4] = f2bf(pv[hf * 2 + 1][j]);
            }

#pragma unroll
        for (int hf = 0; hf < 2; ++hf) {
#pragma unroll
            for (int dc = 0; dc < 4; ++dc) {
                const int d  = dc * 16 + l15;
                const int s0 = (((hf * 8) + h)     ^ l15) << 2;
                const int s1 = (((hf * 8) + 4 + h) ^ l15) << 2;
                bf16x4 r0 = *(const bf16x4*)(vr_s + d * 64 + s0);
                bf16x4 r1 = *(const bf16x4*)(vr_s + d * 64 + s1);
                bf16x4 i0 = *(const bf16x4*)(vi_s + d * 64 + s0);
                bf16x4 i1 = *(const bf16x4*)(vi_s + d * 64 + s1);
                bf16x8 av, ai;
#pragma unroll
                for (int j = 0; j < 4; ++j) {
                    av[j] = r0[j]; av[j + 4] = r1[j];
                    ai[j] = i0[j]; ai[j + 4] = i1[j];
                }
                o_re[dc] = MFMA(av, pb[hf], o_re[dc]);
                o_im[dc] = MFMA(ai, pb[hf], o_im[dc]);
            }
        }
        __syncthreads();
    }

    float lt = l_run;
    lt += __shfl_xor(lt, 16);
    lt += __shfl_xor(lt, 32);
    const float inv = 1.0f / lt;

    float* ol = (float*)smem;
    auto store_comp = [&](const f32x4 (&oc)[4], float* og) {
#pragma unroll
        for (int dc = 0; dc < 4; ++dc)
#pragma unroll
            for (int r = 0; r < 4; ++r)
                ol[(wv * 16 + l15) * 65 + dc * 16 + h * 4 + r] = oc[dc][r] * inv;
        __syncthreads();
#pragma unroll
        for (int i = 0; i < 4; ++i) {
            const int slot = i * 256 + tid;
            const int row  = slot >> 4;
            const int c4   = slot & 15;
            f32x4 v;
#pragma unroll
            for (int j = 0; j < 4; ++j) v[j] = ol[row * 65 + c4 * 4 + j];
            *(f32x4*)(og + (size_t)row * D_ + c4 * 4) = v;
        }
        __syncthreads();
    };

    float* og0 = out + boff + (size_t)(qb * QBLK) * D_;
    store_comp(o_re, og0);
    store_comp(o_im, og0 + (size_t)B_ * S_ * D_);
}

extern "C" void kernel_launch(void* const* d_in, const int* in_sizes, int n_in,
                              void* d_out, int out_size, void* d_ws, size_t ws_size,
                              hipStream_t stream) {
    (void)in_sizes; (void)n_in; (void)out_size;
    const float* q_re = (const float*)d_in[0];
    const float* q_im = (const float*)d_in[1];
    const float* k_re = (const float*)d_in[2];
    const float* k_im = (const float*)d_in[3];
    const float* v_re = (const float*)d_in[4];
    const float* v_im = (const float*)d_in[5];
    float* out = (float*)d_out;

    const size_t bf_bytes = 6 * (size_t)NELEM * 2;                 // 12 MiB staging
    const size_t need8f32 = bf_bytes + 8 * 2 * (size_t)NELEM * 4 + 8 * (size_t)BS_ * 8;
    const size_t need8f16 = bf_bytes + 8 * 2 * (size_t)NELEM * 2 + 8 * (size_t)BS_ * 8;
    const size_t need4f32 = bf_bytes + 4 * 2 * (size_t)NELEM * 4 + 4 * (size_t)BS_ * 8;

    if (ws_size >= bf_bytes) {
        short* wsb = (short*)d_ws;
        prepass_kernel<<<4608, 256, 0, stream>>>(q_re, q_im, k_re, k_im, v_re, v_im, wsb);
        char* extra = (char*)d_ws + bf_bytes;
        if (ws_size >= need8f32) {
            float* opart = (float*)extra;
            float* ml    = (float*)(extra + 8 * 2 * (size_t)NELEM * 4);
            cv_attn_main<8, float><<<B_ * 64 * 8, 256, 0, stream>>>(wsb, nullptr, opart, ml);
            cv_attn_combine<8, float><<<2048, 256, 0, stream>>>(opart, ml, out);
        } else if (ws_size >= need8f16) {
            _Float16* opart = (_Float16*)extra;
            float* ml = (float*)(extra + 8 * 2 * (size_t)NELEM * 2);
            cv_attn_main<8, _Float16><<<B_ * 64 * 8, 256, 0, stream>>>(wsb, nullptr, opart, ml);
            cv_attn_combine<8, _Float16><<<2048, 256, 0, stream>>>(opart, ml, out);
        } else if (ws_size >= need4f32) {
            float* opart = (float*)extra;
            float* ml    = (float*)(extra + 4 * 2 * (size_t)NELEM * 4);
            cv_attn_main<4, float><<<B_ * 64 * 4, 256, 0, stream>>>(wsb, nullptr, opart, ml);
            cv_attn_combine<4, float><<<2048, 256, 0, stream>>>(opart, ml, out);
        } else {
            cv_attn_main<1, float><<<B_ * 64, 256, 0, stream>>>(wsb, out, out, nullptr);
        }
    } else {
        cv_attn_legacy<<<B_ * 64, 256, 0, stream>>>(q_re, q_im, k_re, k_im, v_re, v_im, out);
    }
}

// Round 6
// 81.025 us; speedup vs baseline: 1.0912x; 1.0912x over previous
//
#include <hip/hip_runtime.h>
#include <stdint.h>

#define B_    4
#define S_    4096
#define D_    64
#define QBLK  64
#define KVBLK 64
#define NT    (S_ / KVBLK)
#define NELEM (B_ * S_ * D_)   // 1048576 per tensor
#define BS_   (B_ * S_)        // 16384

typedef __attribute__((ext_vector_type(8))) short bf16x8;
typedef __attribute__((ext_vector_type(4))) short bf16x4;
typedef __attribute__((ext_vector_type(4))) float f32x4;
typedef __attribute__((ext_vector_type(4))) int   i32x4;
typedef __attribute__((ext_vector_type(4))) unsigned u32x4;
typedef __attribute__((ext_vector_type(4))) _Float16 f16x4;

#define MFMA(a, b, c) __builtin_amdgcn_mfma_f32_16x16x32_bf16(a, b, c, 0, 0, 0)
#define VMWAIT(n) asm volatile("s_waitcnt vmcnt(" #n ")" ::: "memory")
#define BARRIER() do { asm volatile("" ::: "memory"); __builtin_amdgcn_s_barrier(); asm volatile("" ::: "memory"); } while (0)
// Read-retirement fence before releasing LDS writers (rule #18).
#define LGKM_FENCE() do { asm volatile("s_waitcnt lgkmcnt(0)" ::: "memory"); __builtin_amdgcn_sched_barrier(0); } while (0)

__device__ __forceinline__ short f2bf(float x) {
    unsigned u = __builtin_bit_cast(unsigned, x);
    u += 0x7FFFu + ((u >> 16) & 1u);
    return (short)(u >> 16);
}

__device__ __forceinline__ unsigned cvtpk(float lo, float hi) {
    unsigned r;
    asm("v_cvt_pk_bf16_f32 %0, %1, %2" : "=v"(r) : "v"(lo), "v"(hi));
    return r;
}

__device__ __forceinline__ void async16(const short* g, short* l) {
    __builtin_amdgcn_global_load_lds(
        (const __attribute__((address_space(1))) unsigned int*)g,
        (__attribute__((address_space(3))) unsigned int*)l, 16, 0, 0);
}

// ---------------- merged pre-pass (unchanged from round 5, passed) ----------------
__global__ __launch_bounds__(256)
void prepass_kernel(const float* __restrict__ q_re, const float* __restrict__ q_im,
                    const float* __restrict__ k_re, const float* __restrict__ k_im,
                    const float* __restrict__ v_re, const float* __restrict__ v_im,
                    short* __restrict__ ws) {
    const int bidx = blockIdx.x;
    const int tid  = threadIdx.x;
    if (bidx < 4096) {
        const int idx = bidx * 256 + tid;               // f32x4 slots
        const int tn  = idx >> 18;
        const int e4  = idx & ((1 << 18) - 1);
        const float* s = (tn == 0 ? q_re : tn == 1 ? q_im : tn == 2 ? k_re : k_im)
                         + (size_t)e4 * 4;
        const float sc = (tn < 2) ? 0.125f : 1.0f;      // fold softmax scale into Q
        f32x4 x = *(const f32x4*)s;
        bf16x4 v;
#pragma unroll
        for (int c = 0; c < 4; ++c) v[c] = f2bf(x[c] * sc);
        *(bf16x4*)(ws + (size_t)tn * NELEM + (size_t)e4 * 4) = v;
    } else {
        __shared__ short tile[64][72];
        const int tb   = bidx - 4096;       // 0..511
        const int sb   = tb & 63;
        const int b    = (tb >> 6) & 3;
        const int comp = tb >> 8;
        const float* src = comp ? v_im : v_re;
        short* dst = ws + (size_t)(4 + comp) * NELEM;
#pragma unroll
        for (int i = 0; i < 4; ++i) {
            const int slot = i * 256 + tid;
            const int s  = slot >> 4;
            const int d4 = slot & 15;
            f32x4 x = *(const f32x4*)(src + (((size_t)b * S_) + sb * 64 + s) * D_ + d4 * 4);
#pragma unroll
            for (int c = 0; c < 4; ++c) tile[d4 * 4 + c][s] = f2bf(x[c]);
        }
        __syncthreads();
#pragma unroll
        for (int i = 0; i < 2; ++i) {
            const int slot = i * 256 + tid;
            const int d = slot >> 3;
            const int m = slot & 7;               // pos-group (8 consecutive pos)
            const int a = m >> 2, hh = m & 3;     // key = 32a + 4hh + 16(j>>2) + (j&3)
            bf16x8 v;
#pragma unroll
            for (int j = 0; j < 8; ++j)
                v[j] = tile[d][a * 32 + hh * 4 + ((j >> 2) << 4) + (j & 3)];
            *(bf16x8*)(dst + ((size_t)b * 64 + d) * S_ + sb * 64 + m * 8) = v;
        }
    }
}

// ---------------- main flash kernel: double-buffered, ONE barrier per tile ----------------
template<int SPLIT, typename OT>
__global__ __launch_bounds__(256, 2)
void cv_attn_main(const short* __restrict__ wsb,
                  float* __restrict__ out,
                  OT* __restrict__ opart,
                  float* __restrict__ ml)
{
    // 2 buffers x (kr|ki|vr|vi), each array KVBLK*64 shorts. 64 KiB total.
    __shared__ __align__(16) short smem[2 * 4 * KVBLK * D_];

    const int tid  = threadIdx.x;
    const int lane = tid & 63;
    const int wv   = tid >> 6;
    const int l15  = lane & 15;
    const int h    = lane >> 4;

    int bid = blockIdx.x;
    const int nwg = B_ * 64 * SPLIT;
    bid = (bid & 7) * (nwg >> 3) + (bid >> 3);
    const int qb = bid & 63;
    const int sp = (bid >> 6) % SPLIT;
    const int b  = bid / (64 * SPLIT);

    const short* qr  = wsb;
    const short* qi  = wsb + (size_t)NELEM;
    const short* kr  = wsb + 2 * (size_t)NELEM;
    const short* ki  = wsb + 3 * (size_t)NELEM;
    const short* vrT = wsb + 4 * (size_t)NELEM;
    const short* viT = wsb + 5 * (size_t)NELEM;

    // Unified LDS read bases (shorts); all array/buffer/c steps are ds-offset immediates.
    short* kb0 = smem + l15 * 64 + ((h ^ (l15 & 7)) << 3);
    short* kb1 = smem + l15 * 64 + (((h ^ 4) ^ (l15 & 7)) << 3);

    // persistent Q fragments (already scaled by 0.125)
    const int qrow = qb * QBLK + wv * 16 + l15;
    const size_t qoff = ((size_t)b * S_ + qrow) * D_;
    bf16x8 fqr[2], fqi[2], fqn[2];
#pragma unroll
    for (int dh = 0; dh < 2; ++dh) {
        fqr[dh] = *(const bf16x8*)(qr + qoff + dh * 32 + h * 8);
        fqi[dh] = *(const bf16x8*)(qi + qoff + dh * 32 + h * 8);
        i32x4 n = __builtin_bit_cast(i32x4, fqi[dh]) ^ (int)0x80008000;
        fqn[dh] = __builtin_bit_cast(bf16x8, n);
    }

    f32x4 o_re[4], o_im[4];
#pragma unroll
    for (int i = 0; i < 4; ++i) {
        o_re[i] = (f32x4){0.f, 0.f, 0.f, 0.f};
        o_im[i] = (f32x4){0.f, 0.f, 0.f, 0.f};
    }
    float m_run = -1e30f, l_run = 0.f;
    const float L2E = 1.44269504088896f;

    const int r8   = lane >> 3;
    const int u16l = lane & 7;
    constexpr int TPB = NT / SPLIT;            // even (16 for SPLIT=4)

    // stage tile t into buffer at short-offset DST (0 or 16384)
    auto stage = [&](int t, int DST) {
        const int kb = (sp * TPB + t) * KVBLK;
#pragma unroll
        for (int i = 0; i < 2; ++i) {
            const int row   = wv * 16 + i * 8 + r8;
            const int lbase = (wv * 16 + i * 8) * 64;
            const int swz   = (u16l ^ (row & 7)) << 3;
            const size_t koff = ((size_t)b * S_ + kb + row) * 64 + swz;
            async16(kr + koff, smem + DST + lbase);
            async16(ki + koff, smem + DST + 4096 + lbase);
            const size_t voff = ((size_t)b * 64 + row) * S_ + kb + swz;
            async16(vrT + voff, smem + DST + 8192 + lbase);
            async16(viT + voff, smem + DST + 12288 + lbase);
        }
    };

    auto body = [&](int t, int CUR, int OTH) {
        // stage(t) was issued one full tile ago -> ~0 stall; my t-1 LDS reads
        // must retire before releasing buf[OTH]'s writers (rule #18 fence).
        VMWAIT(0);
        LGKM_FENCE();
        BARRIER();
        if (t + 1 < TPB) stage(t + 1, OTH);    // flies under this whole tile

        // ---- scores: S^T = K * Q^T ----
        f32x4 s_re[4], s_im[4];
#pragma unroll
        for (int c = 0; c < 4; ++c) {
            s_re[c] = (f32x4){0.f, 0.f, 0.f, 0.f};
            s_im[c] = (f32x4){0.f, 0.f, 0.f, 0.f};
        }
        __builtin_amdgcn_s_setprio(1);
#pragma unroll
        for (int c = 0; c < 4; ++c) {
            bf16x8 fkr0 = *(const bf16x8*)(kb0 + CUR + c * 1024);
            bf16x8 fkr1 = *(const bf16x8*)(kb1 + CUR + c * 1024);
            bf16x8 fki0 = *(const bf16x8*)(kb0 + CUR + 4096 + c * 1024);
            bf16x8 fki1 = *(const bf16x8*)(kb1 + CUR + 4096 + c * 1024);
            s_re[c] = MFMA(fkr0, fqr[0], s_re[c]);
            s_re[c] = MFMA(fkr1, fqr[1], s_re[c]);
            s_re[c] = MFMA(fki0, fqn[0], s_re[c]);
            s_re[c] = MFMA(fki1, fqn[1], s_re[c]);
            s_im[c] = MFMA(fki0, fqr[0], s_im[c]);
            s_im[c] = MFMA(fki1, fqr[1], s_im[c]);
            s_im[c] = MFMA(fkr0, fqi[0], s_im[c]);
            s_im[c] = MFMA(fkr1, fqi[1], s_im[c]);
        }
        __builtin_amdgcn_s_setprio(0);

        // ---- magnitude (s_re <- mg) ----
#pragma unroll
        for (int c = 0; c < 4; ++c) {
            f32x4 g = s_re[c] * s_re[c] + s_im[c] * s_im[c];
#pragma unroll
            for (int r = 0; r < 4; ++r) s_re[c][r] = __builtin_amdgcn_sqrtf(g[r]);
        }
        float tmax = s_re[0][0];
#pragma unroll
        for (int c = 0; c < 4; ++c)
#pragma unroll
            for (int r = 0; r < 4; ++r) tmax = fmaxf(tmax, s_re[c][r]);
        tmax = fmaxf(tmax, __shfl_xor(tmax, 16));
        tmax = fmaxf(tmax, __shfl_xor(tmax, 32));

        // ---- defer-max (T13) ----
        if (__any(tmax > m_run + 8.0f)) {
            const float m_new = fmaxf(m_run, tmax);
            const float alpha = __builtin_amdgcn_exp2f((m_run - m_new) * L2E);
            l_run *= alpha;
#pragma unroll
            for (int i = 0; i < 4; ++i) { o_re[i] *= alpha; o_im[i] *= alpha; }
            m_run = m_new;
        }
        const float nm = -m_run * L2E;

        // ---- p = exp2(mg*L2E + nm)  (s_im <- p) ----
#pragma unroll
        for (int c = 0; c < 4; ++c)
#pragma unroll
            for (int r = 0; r < 4; ++r)
                s_im[c][r] = __builtin_amdgcn_exp2f(__builtin_fmaf(s_re[c][r], L2E, nm));
        f32x4 ps = s_im[0] + s_im[1] + s_im[2] + s_im[3];
        l_run += (ps[0] + ps[1]) + (ps[2] + ps[3]);

        // ---- pack P ----
        bf16x8 pb[2];
#pragma unroll
        for (int hf = 0; hf < 2; ++hf) {
            u32x4 w;
            w[0] = cvtpk(s_im[hf * 2][0],     s_im[hf * 2][1]);
            w[1] = cvtpk(s_im[hf * 2][2],     s_im[hf * 2][3]);
            w[2] = cvtpk(s_im[hf * 2 + 1][0], s_im[hf * 2 + 1][1]);
            w[3] = cvtpk(s_im[hf * 2 + 1][2], s_im[hf * 2 + 1][3]);
            pb[hf] = __builtin_bit_cast(bf16x8, w);
        }

        // ---- PV (permuted-key layout: one b128 per fragment) ----
        __builtin_amdgcn_s_setprio(1);
#pragma unroll
        for (int hf = 0; hf < 2; ++hf) {
            const short* kbh = hf ? kb1 : kb0;
#pragma unroll
            for (int dc = 0; dc < 4; ++dc) {
                bf16x8 av = *(const bf16x8*)(kbh + CUR + 8192  + dc * 1024);
                bf16x8 ai = *(const bf16x8*)(kbh + CUR + 12288 + dc * 1024);
                o_re[dc] = MFMA(av, pb[hf], o_re[dc]);
                o_im[dc] = MFMA(ai, pb[hf], o_im[dc]);
            }
        }
        __builtin_amdgcn_s_setprio(0);
    };

    stage(0, 0);
    for (int tt = 0; tt < TPB; tt += 2) {
        body(tt,     0,     16384);
        body(tt + 1, 16384, 0);
    }

    // ---------------- epilogue: normalized output ----------------
    float lt = l_run;
    lt += __shfl_xor(lt, 16);
    lt += __shfl_xor(lt, 32);
    const float inv = 1.0f / lt;

    float* ol = (float*)smem;   // 64 x 65 f32 overlay

    OT* dst_re;
    OT* dst_im;
    if constexpr (SPLIT == 1) {
        dst_re = (OT*)out + ((size_t)b * S_ + qb * QBLK) * D_;
        dst_im = dst_re + (size_t)NELEM;
    } else {
        const size_t qo = ((size_t)b * S_ + qb * QBLK) * D_;
        dst_re = opart + ((size_t)sp * 2 + 0) * NELEM + qo;
        dst_im = opart + ((size_t)sp * 2 + 1) * NELEM + qo;
    }

    auto store_comp = [&](const f32x4 (&oc)[4], OT* og) {
        __syncthreads();
#pragma unroll
        for (int dc = 0; dc < 4; ++dc)
#pragma unroll
            for (int r = 0; r < 4; ++r)
                ol[(wv * 16 + l15) * 65 + dc * 16 + h * 4 + r] = oc[dc][r] * inv;
        __syncthreads();
#pragma unroll
        for (int i = 0; i < 4; ++i) {
            const int slot = i * 256 + tid;
            const int row  = slot >> 4;
            const int c4   = slot & 15;
            f32x4 v;
#pragma unroll
            for (int j = 0; j < 4; ++j) v[j] = ol[row * 65 + c4 * 4 + j];
            if constexpr (sizeof(OT) == 4) {
                *(f32x4*)((float*)og + (size_t)row * D_ + c4 * 4) = v;
            } else {
                f16x4 hv;
#pragma unroll
                for (int j = 0; j < 4; ++j) hv[j] = (_Float16)v[j];
                *(f16x4*)((_Float16*)og + (size_t)row * D_ + c4 * 4) = hv;
            }
        }
    };
    store_comp(o_re, dst_re);
    store_comp(o_im, dst_im);

    if constexpr (SPLIT > 1) {
        if (lane < 16) {
            const int row = qb * QBLK + wv * 16 + lane;
            const size_t mo = ((size_t)sp * BS_ + (size_t)b * S_ + row) * 2;
            ml[mo]     = m_run;
            ml[mo + 1] = lt;
        }
    }
}

// ---------------- combine: out = sum_s w_s * Ohat_s / sum_s w_s, w_s = l_s * 2^((m_s-M)L2E) ----------------
template<int SPLIT, typename OT>
__global__ __launch_bounds__(256)
void cv_attn_combine(const OT* __restrict__ opart, const float* __restrict__ ml,
                     float* __restrict__ out) {
    const int idx  = blockIdx.x * 256 + threadIdx.x;
    const int d4   = idx & 15;
    const int rest = idx >> 4;
    const int row  = rest & (BS_ - 1);
    const int comp = rest >> 14;
    float ms[SPLIT], ls[SPLIT];
    float M = -1e30f;
#pragma unroll
    for (int s = 0; s < SPLIT; ++s) {
        ms[s] = ml[((size_t)s * BS_ + row) * 2];
        ls[s] = ml[((size_t)s * BS_ + row) * 2 + 1];
        M = fmaxf(M, ms[s]);
    }
    float W = 0.f;
    f32x4 acc = (f32x4){0.f, 0.f, 0.f, 0.f};
#pragma unroll
    for (int s = 0; s < SPLIT; ++s) {
        const float w = ls[s] * __builtin_amdgcn_exp2f((ms[s] - M) * 1.44269504088896f);
        W += w;
        const OT* op = opart + ((size_t)(s * 2 + comp)) * NELEM + (size_t)row * D_ + d4 * 4;
        f32x4 o;
        if constexpr (sizeof(OT) == 4) {
            o = *(const f32x4*)op;
        } else {
            f16x4 hv = *(const f16x4*)op;
#pragma unroll
            for (int j = 0; j < 4; ++j) o[j] = (float)hv[j];
        }
        acc += o * w;
    }
    acc *= (1.0f / W);
    *(f32x4*)(out + (size_t)comp * NELEM + (size_t)row * D_ + d4 * 4) = acc;
}

// ---------------- legacy fallback (f32 direct, self-contained) ----------------
__global__ __launch_bounds__(256, 1)
void cv_attn_legacy(const float* __restrict__ q_re, const float* __restrict__ q_im,
                    const float* __restrict__ k_re, const float* __restrict__ k_im,
                    const float* __restrict__ v_re, const float* __restrict__ v_im,
                    float* __restrict__ out)
{
    __shared__ __align__(16) short smem[4 * KVBLK * D_];
    short* kr_s = smem;
    short* ki_s = smem + 4096;
    short* vr_s = smem + 8192;
    short* vi_s = smem + 12288;

    const int tid  = threadIdx.x;
    const int lane = tid & 63;
    const int wv   = tid >> 6;
    const int l15  = lane & 15;
    const int h    = lane >> 4;

    const int b  = blockIdx.x >> 6;
    const int qb = blockIdx.x & 63;
    const size_t boff = (size_t)b * S_ * D_;

    const int qrow = qb * QBLK + wv * 16 + l15;
    const float* qrp = q_re + boff + (size_t)qrow * D_;
    const float* qip = q_im + boff + (size_t)qrow * D_;
    bf16x8 fqr[2], fqi[2], fqn[2];
#pragma unroll
    for (int dh = 0; dh < 2; ++dh) {
        const int d0 = dh * 32 + h * 8;
        f32x4 a0 = *(const f32x4*)(qrp + d0);
        f32x4 a1 = *(const f32x4*)(qrp + d0 + 4);
        f32x4 b0 = *(const f32x4*)(qip + d0);
        f32x4 b1 = *(const f32x4*)(qip + d0 + 4);
#pragma unroll
        for (int j = 0; j < 4; ++j) {
            fqr[dh][j] = f2bf(a0[j]); fqr[dh][j + 4] = f2bf(a1[j]);
            fqi[dh][j] = f2bf(b0[j]); fqi[dh][j + 4] = f2bf(b1[j]);
            fqn[dh][j] = f2bf(-b0[j]); fqn[dh][j + 4] = f2bf(-b1[j]);
        }
    }

    f32x4 o_re[4], o_im[4];
#pragma unroll
    for (int i = 0; i < 4; ++i) {
        o_re[i] = (f32x4){0.f, 0.f, 0.f, 0.f};
        o_im[i] = (f32x4){0.f, 0.f, 0.f, 0.f};
    }
    float m_run = -1e30f, l_run = 0.f;
    const float SC = 0.125f * 1.44269504088896f;

    for (int t = 0; t < NT; ++t) {
        const int kb = t * KVBLK;
#pragma unroll
        for (int a = 0; a < 2; ++a) {
            const float* src = (a ? k_im : k_re) + boff;
            short* dst = a ? ki_s : kr_s;
#pragma unroll
            for (int i = 0; i < 2; ++i) {
                const int slot = i * 256 + tid;
                const int row  = slot >> 3;
                const int cb   = slot & 7;
                const float* p = src + (size_t)(kb + row) * D_ + cb * 8;
                f32x4 x0 = *(const f32x4*)p;
                f32x4 x1 = *(const f32x4*)(p + 4);
                bf16x8 v;
#pragma unroll
                for (int j = 0; j < 4; ++j) { v[j] = f2bf(x0[j]); v[j + 4] = f2bf(x1[j]); }
                *(bf16x8*)(dst + row * 64 + ((cb ^ (row & 7)) << 3)) = v;
            }
        }
#pragma unroll
        for (int a = 0; a < 2; ++a) {
            const float* src = (a ? v_im : v_re) + boff;
            short* dst = a ? vi_s : vr_s;
#pragma unroll
            for (int i = 0; i < 4; ++i) {
                const int slot = i * 256 + tid;
                const int k  = slot >> 4;
                const int d4 = slot & 15;
                f32x4 x = *(const f32x4*)(src + (size_t)(kb + k) * D_ + d4 * 4);
#pragma unroll
                for (int c = 0; c < 4; ++c) {
                    const int d = d4 * 4 + c;
                    dst[d * 64 + (((k >> 2) ^ (d & 15)) << 2) + (k & 3)] = f2bf(x[c]);
                }
            }
        }
        __syncthreads();

        f32x4 s_re[4], s_im[4];
#pragma unroll
        for (int c = 0; c < 4; ++c) {
            s_re[c] = (f32x4){0.f, 0.f, 0.f, 0.f};
            s_im[c] = (f32x4){0.f, 0.f, 0.f, 0.f};
        }
#pragma unroll
        for (int c = 0; c < 4; ++c) {
            const int krow = c * 16 + l15;
#pragma unroll
            for (int dh = 0; dh < 2; ++dh) {
                const int u = ((dh * 4 + h) ^ (krow & 7)) << 3;
                bf16x8 fkr = *(const bf16x8*)(kr_s + krow * 64 + u);
                bf16x8 fki = *(const bf16x8*)(ki_s + krow * 64 + u);
                s_re[c] = MFMA(fkr, fqr[dh], s_re[c]);
                s_re[c] = MFMA(fki, fqn[dh], s_re[c]);
                s_im[c] = MFMA(fki, fqr[dh], s_im[c]);
                s_im[c] = MFMA(fkr, fqi[dh], s_im[c]);
            }
        }

        float pv[4][4];
        float tmax = 0.f;
#pragma unroll
        for (int c = 0; c < 4; ++c)
#pragma unroll
            for (int r = 0; r < 4; ++r) {
                const float re = s_re[c][r], im = s_im[c][r];
                const float mg = __builtin_amdgcn_sqrtf(re * re + im * im) * SC;
                pv[c][r] = mg;
                tmax = fmaxf(tmax, mg);
            }
        tmax = fmaxf(tmax, __shfl_xor(tmax, 16));
        tmax = fmaxf(tmax, __shfl_xor(tmax, 32));
        const float m_new = fmaxf(m_run, tmax);
        const float alpha = __builtin_amdgcn_exp2f(m_run - m_new);
        m_run = m_new;
        float psum = 0.f;
#pragma unroll
        for (int c = 0; c < 4; ++c)
#pragma unroll
            for (int r = 0; r < 4; ++r) {
                const float e = __builtin_amdgcn_exp2f(pv[c][r] - m_new);
                pv[c][r] = e;
                psum += e;
            }
        l_run = l_run * alpha + psum;
#pragma unroll
        for (int i = 0; i < 4; ++i) { o_re[i] *= alpha; o_im[i] *= alpha; }

        bf16x8 pb[2];
#pragma unroll
        for (int hf = 0; hf < 2; ++hf)
#pragma unroll
            for (int j = 0; j < 4; ++j) {
                pb[hf][j]     = f2bf(pv[hf * 2][j]);
                pb[hf][j + 4] = f2bf(pv[hf * 2 + 1][j]);
            }

#pragma unroll
        for (int hf = 0; hf < 2; ++hf) {
#pragma unroll
            for (int dc = 0; dc < 4; ++dc) {
                const int d  = dc * 16 + l15;
                const int s0 = (((hf * 8) + h)     ^ l15) << 2;
                const int s1 = (((hf * 8) + 4 + h) ^ l15) << 2;
                bf16x4 r0 = *(const bf16x4*)(vr_s + d * 64 + s0);
                bf16x4 r1 = *(const bf16x4*)(vr_s + d * 64 + s1);
                bf16x4 i0 = *(const bf16x4*)(vi_s + d * 64 + s0);
                bf16x4 i1 = *(const bf16x4*)(vi_s + d * 64 + s1);
                bf16x8 av, ai;
#pragma unroll
                for (int j = 0; j < 4; ++j) {
                    av[j] = r0[j]; av[j + 4] = r1[j];
                    ai[j] = i0[j]; ai[j + 4] = i1[j];
                }
                o_re[dc] = MFMA(av, pb[hf], o_re[dc]);
                o_im[dc] = MFMA(ai, pb[hf], o_im[dc]);
            }
        }
        __syncthreads();
    }

    float lt = l_run;
    lt += __shfl_xor(lt, 16);
    lt += __shfl_xor(lt, 32);
    const float inv = 1.0f / lt;

    float* ol = (float*)smem;
    auto store_comp = [&](const f32x4 (&oc)[4], float* og) {
#pragma unroll
        for (int dc = 0; dc < 4; ++dc)
#pragma unroll
            for (int r = 0; r < 4; ++r)
                ol[(wv * 16 + l15) * 65 + dc * 16 + h * 4 + r] = oc[dc][r] * inv;
        __syncthreads();
#pragma unroll
        for (int i = 0; i < 4; ++i) {
            const int slot = i * 256 + tid;
            const int row  = slot >> 4;
            const int c4   = slot & 15;
            f32x4 v;
#pragma unroll
            for (int j = 0; j < 4; ++j) v[j] = ol[row * 65 + c4 * 4 + j];
            *(f32x4*)(og + (size_t)row * D_ + c4 * 4) = v;
        }
        __syncthreads();
    };

    float* og0 = out + boff + (size_t)(qb * QBLK) * D_;
    store_comp(o_re, og0);
    store_comp(o_im, og0 + (size_t)B_ * S_ * D_);
}

extern "C" void kernel_launch(void* const* d_in, const int* in_sizes, int n_in,
                              void* d_out, int out_size, void* d_ws, size_t ws_size,
                              hipStream_t stream) {
    (void)in_sizes; (void)n_in; (void)out_size;
    const float* q_re = (const float*)d_in[0];
    const float* q_im = (const float*)d_in[1];
    const float* k_re = (const float*)d_in[2];
    const float* k_im = (const float*)d_in[3];
    const float* v_re = (const float*)d_in[4];
    const float* v_im = (const float*)d_in[5];
    float* out = (float*)d_out;

    const size_t bf_bytes = 6 * (size_t)NELEM * 2;                 // 12 MiB staging
    const size_t mlsz     = 4 * (size_t)BS_ * 8;                   // 512 KiB
    const size_t need4f16 = bf_bytes + 4 * 2 * (size_t)NELEM * 2 + mlsz;
    const size_t need4f32 = bf_bytes + 4 * 2 * (size_t)NELEM * 4 + mlsz;

    if (ws_size >= bf_bytes) {
        short* wsb = (short*)d_ws;
        prepass_kernel<<<4608, 256, 0, stream>>>(q_re, q_im, k_re, k_im, v_re, v_im, wsb);
        char* extra = (char*)d_ws + bf_bytes;
        if (ws_size >= need4f16) {
            _Float16* opart = (_Float16*)extra;
            float* ml = (float*)(extra + 4 * 2 * (size_t)NELEM * 2);
            cv_attn_main<4, _Float16><<<B_ * 64 * 4, 256, 0, stream>>>(wsb, nullptr, opart, ml);
            cv_attn_combine<4, _Float16><<<2048, 256, 0, stream>>>(opart, ml, out);
        } else if (ws_size >= need4f32) {
            float* opart = (float*)extra;
            float* ml    = (float*)(extra + 4 * 2 * (size_t)NELEM * 4);
            cv_attn_main<4, float><<<B_ * 64 * 4, 256, 0, stream>>>(wsb, nullptr, opart, ml);
            cv_attn_combine<4, float><<<2048, 256, 0, stream>>>(opart, ml, out);
        } else {
            cv_attn_main<1, float><<<B_ * 64, 256, 0, stream>>>(wsb, out, out, nullptr);
        }
    } else {
        cv_attn_legacy<<<B_ * 64, 256, 0, stream>>>(q_re, q_im, k_re, k_im, v_re, v_im, out);
    }
}

// Round 7
// 80.408 us; speedup vs baseline: 1.0995x; 1.0077x over previous
//
#include <hip/hip_runtime.h>
#include <stdint.h>

#define B_    4
#define S_    4096
#define D_    64
#define QBLK  64
#define NELEM (B_ * S_ * D_)   // 1048576 per tensor
#define BS_   (B_ * S_)        // 16384

typedef __attribute__((ext_vector_type(8))) short bf16x8;
typedef __attribute__((ext_vector_type(4))) short bf16x4;
typedef __attribute__((ext_vector_type(4))) float f32x4;
typedef __attribute__((ext_vector_type(4))) int   i32x4;
typedef __attribute__((ext_vector_type(4))) unsigned u32x4;
typedef __attribute__((ext_vector_type(4))) _Float16 f16x4;

#define MFMA(a, b, c) __builtin_amdgcn_mfma_f32_16x16x32_bf16(a, b, c, 0, 0, 0)
#define VMWAIT(n) asm volatile("s_waitcnt vmcnt(" #n ")" ::: "memory")
#define BARRIER() do { asm volatile("" ::: "memory"); __builtin_amdgcn_s_barrier(); asm volatile("" ::: "memory"); } while (0)
// Read-retirement fence before releasing LDS writers (rule #18).
#define LGKM_FENCE() do { asm volatile("s_waitcnt lgkmcnt(0)" ::: "memory"); __builtin_amdgcn_sched_barrier(0); } while (0)

__device__ __forceinline__ short f2bf(float x) {
    unsigned u = __builtin_bit_cast(unsigned, x);
    u += 0x7FFFu + ((u >> 16) & 1u);
    return (short)(u >> 16);
}

__device__ __forceinline__ unsigned cvtpk(float lo, float hi) {
    unsigned r;
    asm("v_cvt_pk_bf16_f32 %0, %1, %2" : "=v"(r) : "v"(lo), "v"(hi));
    return r;
}

__device__ __forceinline__ void async16(const short* g, short* l) {
    __builtin_amdgcn_global_load_lds(
        (const __attribute__((address_space(1))) unsigned int*)g,
        (__attribute__((address_space(3))) unsigned int*)l, 16, 0, 0);
}

// ---------------- merged pre-pass (unchanged from rounds 5/6, passed) ----------------
// V permutation: within each 32-key half, position p5 = h*8+j holds key
// 16*(j>>2) + 4*h + (j&3) -> PV A-fragment is one contiguous b128 for any KVBLK in {32,64}.
__global__ __launch_bounds__(256)
void prepass_kernel(const float* __restrict__ q_re, const float* __restrict__ q_im,
                    const float* __restrict__ k_re, const float* __restrict__ k_im,
                    const float* __restrict__ v_re, const float* __restrict__ v_im,
                    short* __restrict__ ws) {
    const int bidx = blockIdx.x;
    const int tid  = threadIdx.x;
    if (bidx < 4096) {
        const int idx = bidx * 256 + tid;               // f32x4 slots
        const int tn  = idx >> 18;
        const int e4  = idx & ((1 << 18) - 1);
        const float* s = (tn == 0 ? q_re : tn == 1 ? q_im : tn == 2 ? k_re : k_im)
                         + (size_t)e4 * 4;
        const float sc = (tn < 2) ? 0.125f : 1.0f;      // fold softmax scale into Q
        f32x4 x = *(const f32x4*)s;
        bf16x4 v;
#pragma unroll
        for (int c = 0; c < 4; ++c) v[c] = f2bf(x[c] * sc);
        *(bf16x4*)(ws + (size_t)tn * NELEM + (size_t)e4 * 4) = v;
    } else {
        __shared__ short tile[64][72];
        const int tb   = bidx - 4096;       // 0..511
        const int sb   = tb & 63;
        const int b    = (tb >> 6) & 3;
        const int comp = tb >> 8;
        const float* src = comp ? v_im : v_re;
        short* dst = ws + (size_t)(4 + comp) * NELEM;
#pragma unroll
        for (int i = 0; i < 4; ++i) {
            const int slot = i * 256 + tid;
            const int s  = slot >> 4;
            const int d4 = slot & 15;
            f32x4 x = *(const f32x4*)(src + (((size_t)b * S_) + sb * 64 + s) * D_ + d4 * 4);
#pragma unroll
            for (int c = 0; c < 4; ++c) tile[d4 * 4 + c][s] = f2bf(x[c]);
        }
        __syncthreads();
#pragma unroll
        for (int i = 0; i < 2; ++i) {
            const int slot = i * 256 + tid;
            const int d = slot >> 3;
            const int m = slot & 7;               // pos-group (8 consecutive pos)
            const int a = m >> 2, hh = m & 3;     // key = 32a + 4hh + 16(j>>2) + (j&3)
            bf16x8 v;
#pragma unroll
            for (int j = 0; j < 8; ++j)
                v[j] = tile[d][a * 32 + hh * 4 + ((j >> 2) << 4) + (j & 3)];
            *(bf16x8*)(dst + ((size_t)b * 64 + d) * S_ + sb * 64 + m * 8) = v;
        }
    }
}

// -------- main flash kernel: KVBLK=32, double-buffered (32 KiB), 1 barrier/tile --------
template<int SPLIT, typename OT>
__global__ __launch_bounds__(256, 4)
void cv_attn_main(const short* __restrict__ wsb,
                  float* __restrict__ out,
                  OT* __restrict__ opart,
                  float* __restrict__ ml)
{
    // 2 buffers x (kr:2048 | ki:2048 | vr:2048 | vi:2048) shorts = 32 KiB
    __shared__ __align__(16) short smem[2 * 8192];

    const int tid  = threadIdx.x;
    const int lane = tid & 63;
    const int wv   = tid >> 6;
    const int l15  = lane & 15;
    const int h    = lane >> 4;

    int bid = blockIdx.x;
    const int nwg = B_ * 64 * SPLIT;
    bid = (bid & 7) * (nwg >> 3) + (bid >> 3);
    const int qb = bid & 63;
    const int sp = (bid >> 6) % SPLIT;
    const int b  = bid / (64 * SPLIT);

    const short* qr  = wsb;
    const short* qi  = wsb + (size_t)NELEM;
    const short* kr  = wsb + 2 * (size_t)NELEM;
    const short* ki  = wsb + 3 * (size_t)NELEM;
    const short* vrT = wsb + 4 * (size_t)NELEM;
    const short* viT = wsb + 5 * (size_t)NELEM;

    // LDS read bases; array/buffer/quadrant steps are ds-offset immediates.
    // K rows: 32 x 64 shorts (128B); read unit (grp*4+h)^(l15&7).
    short* kb0 = smem + l15 * 64 + ((h ^ (l15 & 7)) << 3);
    short* kb1 = smem + l15 * 64 + (((h ^ 4) ^ (l15 & 7)) << 3);
    // V rows: 64 x 32 shorts (64B); read unit h^(d&3), d&3 == l15&3.
    short* vb0 = smem + l15 * 32 + ((h ^ (l15 & 3)) << 3);

    // persistent Q fragments (already scaled by 0.125)
    const int qrow = qb * QBLK + wv * 16 + l15;
    const size_t qoff = ((size_t)b * S_ + qrow) * D_;
    bf16x8 fqr[2], fqi[2], fqn[2];
#pragma unroll
    for (int dh = 0; dh < 2; ++dh) {
        fqr[dh] = *(const bf16x8*)(qr + qoff + dh * 32 + h * 8);
        fqi[dh] = *(const bf16x8*)(qi + qoff + dh * 32 + h * 8);
        i32x4 n = __builtin_bit_cast(i32x4, fqi[dh]) ^ (int)0x80008000;
        fqn[dh] = __builtin_bit_cast(bf16x8, n);
    }

    f32x4 o_re[4], o_im[4];
#pragma unroll
    for (int i = 0; i < 4; ++i) {
        o_re[i] = (f32x4){0.f, 0.f, 0.f, 0.f};
        o_im[i] = (f32x4){0.f, 0.f, 0.f, 0.f};
    }
    float m_run = -1e30f, l_run = 0.f;
    const float L2E = 1.44269504088896f;

    // staging thread->slot maps (one async16 per array per thread per tile)
    const int kRow = wv * 8 + (lane >> 3);     // K row 0..31 (within wave: 8 rows)
    const int u8   = lane & 7;                 // K 16B-unit
    const int vD   = wv * 16 + (lane >> 2);    // V d-row 0..63 (within wave: 16 rows)
    const int u4   = lane & 3;                 // V 16B-unit
    constexpr int TPB = (S_ / 32) / SPLIT;     // tiles of 32 keys

    auto stage = [&](int t, int DST) {
        const int kb = (sp * TPB + t) * 32;
        const size_t koff = ((size_t)b * S_ + kb + kRow) * 64 + ((u8 ^ (kRow & 7)) << 3);
        async16(kr + koff, smem + DST + wv * 512);
        async16(ki + koff, smem + DST + 2048 + wv * 512);
        const size_t voff = ((size_t)b * 64 + vD) * S_ + kb + ((u4 ^ (vD & 3)) << 3);
        async16(vrT + voff, smem + DST + 4096 + wv * 512);
        async16(viT + voff, smem + DST + 6144 + wv * 512);
    };

    auto body = [&](int t, int CUR, int OTH) {
        // stage(t) was issued one full tile ago; my t-1 LDS reads must retire
        // before buf[OTH]'s writers are released (rule #18 fence).
        VMWAIT(0);
        LGKM_FENCE();
        BARRIER();
        if (t + 1 < TPB) stage(t + 1, OTH);    // flies under this whole tile

        // ---- scores: S^T = K * Q^T (2 key-quadrants) ----
        f32x4 s_re[2], s_im[2];
#pragma unroll
        for (int c = 0; c < 2; ++c) {
            s_re[c] = (f32x4){0.f, 0.f, 0.f, 0.f};
            s_im[c] = (f32x4){0.f, 0.f, 0.f, 0.f};
        }
        __builtin_amdgcn_s_setprio(1);
#pragma unroll
        for (int c = 0; c < 2; ++c) {
            bf16x8 fkr0 = *(const bf16x8*)(kb0 + CUR + c * 1024);
            bf16x8 fkr1 = *(const bf16x8*)(kb1 + CUR + c * 1024);
            bf16x8 fki0 = *(const bf16x8*)(kb0 + CUR + 2048 + c * 1024);
            bf16x8 fki1 = *(const bf16x8*)(kb1 + CUR + 2048 + c * 1024);
            s_re[c] = MFMA(fkr0, fqr[0], s_re[c]);
            s_re[c] = MFMA(fkr1, fqr[1], s_re[c]);
            s_re[c] = MFMA(fki0, fqn[0], s_re[c]);
            s_re[c] = MFMA(fki1, fqn[1], s_re[c]);
            s_im[c] = MFMA(fki0, fqr[0], s_im[c]);
            s_im[c] = MFMA(fki1, fqr[1], s_im[c]);
            s_im[c] = MFMA(fkr0, fqi[0], s_im[c]);
            s_im[c] = MFMA(fkr1, fqi[1], s_im[c]);
        }
        __builtin_amdgcn_s_setprio(0);

        // ---- magnitude (s_re <- mg) ----
#pragma unroll
        for (int c = 0; c < 2; ++c) {
            f32x4 g = s_re[c] * s_re[c] + s_im[c] * s_im[c];
#pragma unroll
            for (int r = 0; r < 4; ++r) s_re[c][r] = __builtin_amdgcn_sqrtf(g[r]);
        }
        float tmax = fmaxf(fmaxf(fmaxf(s_re[0][0], s_re[0][1]), fmaxf(s_re[0][2], s_re[0][3])),
                           fmaxf(fmaxf(s_re[1][0], s_re[1][1]), fmaxf(s_re[1][2], s_re[1][3])));
        tmax = fmaxf(tmax, __shfl_xor(tmax, 16));
        tmax = fmaxf(tmax, __shfl_xor(tmax, 32));

        // ---- defer-max (T13) ----
        if (__any(tmax > m_run + 8.0f)) {
            const float m_new = fmaxf(m_run, tmax);
            const float alpha = __builtin_amdgcn_exp2f((m_run - m_new) * L2E);
            l_run *= alpha;
#pragma unroll
            for (int i = 0; i < 4; ++i) { o_re[i] *= alpha; o_im[i] *= alpha; }
            m_run = m_new;
        }
        const float nm = -m_run * L2E;

        // ---- p = exp2(mg*L2E + nm)  (s_im <- p) ----
#pragma unroll
        for (int c = 0; c < 2; ++c)
#pragma unroll
            for (int r = 0; r < 4; ++r)
                s_im[c][r] = __builtin_amdgcn_exp2f(__builtin_fmaf(s_re[c][r], L2E, nm));
        f32x4 ps = s_im[0] + s_im[1];
        l_run += (ps[0] + ps[1]) + (ps[2] + ps[3]);

        // ---- pack P: slot j -> key 16(j>>2)+4h+(j&3) = p[j>>2][j&3] ----
        u32x4 w;
        w[0] = cvtpk(s_im[0][0], s_im[0][1]);
        w[1] = cvtpk(s_im[0][2], s_im[0][3]);
        w[2] = cvtpk(s_im[1][0], s_im[1][1]);
        w[3] = cvtpk(s_im[1][2], s_im[1][3]);
        bf16x8 pb = __builtin_bit_cast(bf16x8, w);

        // ---- PV: O^T += V^T * W^T (permuted-key layout, single b128/frag) ----
        __builtin_amdgcn_s_setprio(1);
#pragma unroll
        for (int dc = 0; dc < 4; ++dc) {
            bf16x8 av = *(const bf16x8*)(vb0 + CUR + 4096 + dc * 512);
            bf16x8 ai = *(const bf16x8*)(vb0 + CUR + 6144 + dc * 512);
            o_re[dc] = MFMA(av, pb, o_re[dc]);
            o_im[dc] = MFMA(ai, pb, o_im[dc]);
        }
        __builtin_amdgcn_s_setprio(0);
    };

    stage(0, 0);
    for (int tt = 0; tt < TPB; tt += 2) {
        body(tt,     0,    8192);
        body(tt + 1, 8192, 0);
    }

    // ---------------- epilogue: normalized output ----------------
    float lt = l_run;
    lt += __shfl_xor(lt, 16);
    lt += __shfl_xor(lt, 32);
    const float inv = 1.0f / lt;

    float* ol = (float*)smem;   // 64 x 65 f32 overlay (16.6 KiB < 32 KiB)

    OT* dst_re;
    OT* dst_im;
    if constexpr (SPLIT == 1) {
        dst_re = (OT*)out + ((size_t)b * S_ + qb * QBLK) * D_;
        dst_im = dst_re + (size_t)NELEM;
    } else {
        const size_t qo = ((size_t)b * S_ + qb * QBLK) * D_;
        dst_re = opart + ((size_t)sp * 2 + 0) * NELEM + qo;
        dst_im = opart + ((size_t)sp * 2 + 1) * NELEM + qo;
    }

    auto store_comp = [&](const f32x4 (&oc)[4], OT* og) {
        __syncthreads();
#pragma unroll
        for (int dc = 0; dc < 4; ++dc)
#pragma unroll
            for (int r = 0; r < 4; ++r)
                ol[(wv * 16 + l15) * 65 + dc * 16 + h * 4 + r] = oc[dc][r] * inv;
        __syncthreads();
#pragma unroll
        for (int i = 0; i < 4; ++i) {
            const int slot = i * 256 + tid;
            const int row  = slot >> 4;
            const int c4   = slot & 15;
            f32x4 v;
#pragma unroll
            for (int j = 0; j < 4; ++j) v[j] = ol[row * 65 + c4 * 4 + j];
            if constexpr (sizeof(OT) == 4) {
                *(f32x4*)((float*)og + (size_t)row * D_ + c4 * 4) = v;
            } else {
                f16x4 hv;
#pragma unroll
                for (int j = 0; j < 4; ++j) hv[j] = (_Float16)v[j];
                *(f16x4*)((_Float16*)og + (size_t)row * D_ + c4 * 4) = hv;
            }
        }
    };
    store_comp(o_re, dst_re);
    store_comp(o_im, dst_im);

    if constexpr (SPLIT > 1) {
        if (lane < 16) {
            const int row = qb * QBLK + wv * 16 + lane;
            const size_t mo = ((size_t)sp * BS_ + (size_t)b * S_ + row) * 2;
            ml[mo]     = m_run;
            ml[mo + 1] = lt;
        }
    }
}

// ---- combine: out = sum_s w_s*Ohat_s / sum_s w_s, w_s = l_s * 2^((m_s-M)L2E) ----
template<int SPLIT, typename OT>
__global__ __launch_bounds__(256)
void cv_attn_combine(const OT* __restrict__ opart, const float* __restrict__ ml,
                     float* __restrict__ out) {
    const int idx  = blockIdx.x * 256 + threadIdx.x;
    const int d4   = idx & 15;
    const int rest = idx >> 4;
    const int row  = rest & (BS_ - 1);
    const int comp = rest >> 14;
    float ms[SPLIT], ls[SPLIT];
    float M = -1e30f;
#pragma unroll
    for (int s = 0; s < SPLIT; ++s) {
        ms[s] = ml[((size_t)s * BS_ + row) * 2];
        ls[s] = ml[((size_t)s * BS_ + row) * 2 + 1];
        M = fmaxf(M, ms[s]);
    }
    float W = 0.f;
    f32x4 acc = (f32x4){0.f, 0.f, 0.f, 0.f};
#pragma unroll
    for (int s = 0; s < SPLIT; ++s) {
        const float w = ls[s] * __builtin_amdgcn_exp2f((ms[s] - M) * 1.44269504088896f);
        W += w;
        const OT* op = opart + ((size_t)(s * 2 + comp)) * NELEM + (size_t)row * D_ + d4 * 4;
        f32x4 o;
        if constexpr (sizeof(OT) == 4) {
            o = *(const f32x4*)op;
        } else {
            f16x4 hv = *(const f16x4*)op;
#pragma unroll
            for (int j = 0; j < 4; ++j) o[j] = (float)hv[j];
        }
        acc += o * w;
    }
    acc *= (1.0f / W);
    *(f32x4*)(out + (size_t)comp * NELEM + (size_t)row * D_ + d4 * 4) = acc;
}

// ---------------- legacy fallback (f32 direct, self-contained) ----------------
__global__ __launch_bounds__(256, 1)
void cv_attn_legacy(const float* __restrict__ q_re, const float* __restrict__ q_im,
                    const float* __restrict__ k_re, const float* __restrict__ k_im,
                    const float* __restrict__ v_re, const float* __restrict__ v_im,
                    float* __restrict__ out)
{
    __shared__ __align__(16) short smem[4 * 64 * D_];
    short* kr_s = smem;
    short* ki_s = smem + 4096;
    short* vr_s = smem + 8192;
    short* vi_s = smem + 12288;

    const int tid  = threadIdx.x;
    const int lane = tid & 63;
    const int wv   = tid >> 6;
    const int l15  = lane & 15;
    const int h    = lane >> 4;

    const int b  = blockIdx.x >> 6;
    const int qb = blockIdx.x & 63;
    const size_t boff = (size_t)b * S_ * D_;

    const int qrow = qb * QBLK + wv * 16 + l15;
    const float* qrp = q_re + boff + (size_t)qrow * D_;
    const float* qip = q_im + boff + (size_t)qrow * D_;
    bf16x8 fqr[2], fqi[2], fqn[2];
#pragma unroll
    for (int dh = 0; dh < 2; ++dh) {
        const int d0 = dh * 32 + h * 8;
        f32x4 a0 = *(const f32x4*)(qrp + d0);
        f32x4 a1 = *(const f32x4*)(qrp + d0 + 4);
        f32x4 b0 = *(const f32x4*)(qip + d0);
        f32x4 b1 = *(const f32x4*)(qip + d0 + 4);
#pragma unroll
        for (int j = 0; j < 4; ++j) {
            fqr[dh][j] = f2bf(a0[j]); fqr[dh][j + 4] = f2bf(a1[j]);
            fqi[dh][j] = f2bf(b0[j]); fqi[dh][j + 4] = f2bf(b1[j]);
            fqn[dh][j] = f2bf(-b0[j]); fqn[dh][j + 4] = f2bf(-b1[j]);
        }
    }

    f32x4 o_re[4], o_im[4];
#pragma unroll
    for (int i = 0; i < 4; ++i) {
        o_re[i] = (f32x4){0.f, 0.f, 0.f, 0.f};
        o_im[i] = (f32x4){0.f, 0.f, 0.f, 0.f};
    }
    float m_run = -1e30f, l_run = 0.f;
    const float SC = 0.125f * 1.44269504088896f;

    for (int t = 0; t < S_ / 64; ++t) {
        const int kb = t * 64;
#pragma unroll
        for (int a = 0; a < 2; ++a) {
            const float* src = (a ? k_im : k_re) + boff;
            short* dst = a ? ki_s : kr_s;
#pragma unroll
            for (int i = 0; i < 2; ++i) {
                const int slot = i * 256 + tid;
                const int row  = slot >> 3;
                const int cb   = slot & 7;
                const float* p = src + (size_t)(kb + row) * D_ + cb * 8;
                f32x4 x0 = *(const f32x4*)p;
                f32x4 x1 = *(const f32x4*)(p + 4);
                bf16x8 v;
#pragma unroll
                for (int j = 0; j < 4; ++j) { v[j] = f2bf(x0[j]); v[j + 4] = f2bf(x1[j]); }
                *(bf16x8*)(dst + row * 64 + ((cb ^ (row & 7)) << 3)) = v;
            }
        }
#pragma unroll
        for (int a = 0; a < 2; ++a) {
            const float* src = (a ? v_im : v_re) + boff;
            short* dst = a ? vi_s : vr_s;
#pragma unroll
            for (int i = 0; i < 4; ++i) {
                const int slot = i * 256 + tid;
                const int k  = slot >> 4;
                const int d4 = slot & 15;
                f32x4 x = *(const f32x4*)(src + (size_t)(kb + k) * D_ + d4 * 4);
#pragma unroll
                for (int c = 0; c < 4; ++c) {
                    const int d = d4 * 4 + c;
                    dst[d * 64 + (((k >> 2) ^ (d & 15)) << 2) + (k & 3)] = f2bf(x[c]);
                }
            }
        }
        __syncthreads();

        f32x4 s_re[4], s_im[4];
#pragma unroll
        for (int c = 0; c < 4; ++c) {
            s_re[c] = (f32x4){0.f, 0.f, 0.f, 0.f};
            s_im[c] = (f32x4){0.f, 0.f, 0.f, 0.f};
        }
#pragma unroll
        for (int c = 0; c < 4; ++c) {
            const int krow = c * 16 + l15;
#pragma unroll
            for (int dh = 0; dh < 2; ++dh) {
                const int u = ((dh * 4 + h) ^ (krow & 7)) << 3;
                bf16x8 fkr = *(const bf16x8*)(kr_s + krow * 64 + u);
                bf16x8 fki = *(const bf16x8*)(ki_s + krow * 64 + u);
                s_re[c] = MFMA(fkr, fqr[dh], s_re[c]);
                s_re[c] = MFMA(fki, fqn[dh], s_re[c]);
                s_im[c] = MFMA(fki, fqr[dh], s_im[c]);
                s_im[c] = MFMA(fkr, fqi[dh], s_im[c]);
            }
        }

        float pv[4][4];
        float tmax = 0.f;
#pragma unroll
        for (int c = 0; c < 4; ++c)
#pragma unroll
            for (int r = 0; r < 4; ++r) {
                const float re = s_re[c][r], im = s_im[c][r];
                const float mg = __builtin_amdgcn_sqrtf(re * re + im * im) * SC;
                pv[c][r] = mg;
                tmax = fmaxf(tmax, mg);
            }
        tmax = fmaxf(tmax, __shfl_xor(tmax, 16));
        tmax = fmaxf(tmax, __shfl_xor(tmax, 32));
        const float m_new = fmaxf(m_run, tmax);
        const float alpha = __builtin_amdgcn_exp2f(m_run - m_new);
        m_run = m_new;
        float psum = 0.f;
#pragma unroll
        for (int c = 0; c < 4; ++c)
#pragma unroll
            for (int r = 0; r < 4; ++r) {
                const float e = __builtin_amdgcn_exp2f(pv[c][r] - m_new);
                pv[c][r] = e;
                psum += e;
            }
        l_run = l_run * alpha + psum;
#pragma unroll
        for (int i = 0; i < 4; ++i) { o_re[i] *= alpha; o_im[i] *= alpha; }

        bf16x8 pb[2];
#pragma unroll
        for (int hf = 0; hf < 2; ++hf)
#pragma unroll
            for (int j = 0; j < 4; ++j) {
                pb[hf][j]     = f2bf(pv[hf * 2][j]);
                pb[hf][j + 4] = f2bf(pv[hf * 2 + 1][j]);
            }

#pragma unroll
        for (int hf = 0; hf < 2; ++hf) {
#pragma unroll
            for (int dc = 0; dc < 4; ++dc) {
                const int d  = dc * 16 + l15;
                const int s0 = (((hf * 8) + h)     ^ l15) << 2;
                const int s1 = (((hf * 8) + 4 + h) ^ l15) << 2;
                bf16x4 r0 = *(const bf16x4*)(vr_s + d * 64 + s0);
                bf16x4 r1 = *(const bf16x4*)(vr_s + d * 64 + s1);
                bf16x4 i0 = *(const bf16x4*)(vi_s + d * 64 + s0);
                bf16x4 i1 = *(const bf16x4*)(vi_s + d * 64 + s1);
                bf16x8 av, ai;
#pragma unroll
                for (int j = 0; j < 4; ++j) {
                    av[j] = r0[j]; av[j + 4] = r1[j];
                    ai[j] = i0[j]; ai[j + 4] = i1[j];
                }
                o_re[dc] = MFMA(av, pb[hf], o_re[dc]);
                o_im[dc] = MFMA(ai, pb[hf], o_im[dc]);
            }
        }
        __syncthreads();
    }

    float lt = l_run;
    lt += __shfl_xor(lt, 16);
    lt += __shfl_xor(lt, 32);
    const float inv = 1.0f / lt;

    float* ol = (float*)smem;
    auto store_comp = [&](const f32x4 (&oc)[4], float* og) {
#pragma unroll
        for (int dc = 0; dc < 4; ++dc)
#pragma unroll
            for (int r = 0; r < 4; ++r)
                ol[(wv * 16 + l15) * 65 + dc * 16 + h * 4 + r] = oc[dc][r] * inv;
        __syncthreads();
#pragma unroll
        for (int i = 0; i < 4; ++i) {
            const int slot = i * 256 + tid;
            const int row  = slot >> 4;
            const int c4   = slot & 15;
            f32x4 v;
#pragma unroll
            for (int j = 0; j < 4; ++j) v[j] = ol[row * 65 + c4 * 4 + j];
            *(f32x4*)(og + (size_t)row * D_ + c4 * 4) = v;
        }
        __syncthreads();
    };

    float* og0 = out + boff + (size_t)(qb * QBLK) * D_;
    store_comp(o_re, og0);
    store_comp(o_im, og0 + (size_t)B_ * S_ * D_);
}

extern "C" void kernel_launch(void* const* d_in, const int* in_sizes, int n_in,
                              void* d_out, int out_size, void* d_ws, size_t ws_size,
                              hipStream_t stream) {
    (void)in_sizes; (void)n_in; (void)out_size;
    const float* q_re = (const float*)d_in[0];
    const float* q_im = (const float*)d_in[1];
    const float* k_re = (const float*)d_in[2];
    const float* k_im = (const float*)d_in[3];
    const float* v_re = (const float*)d_in[4];
    const float* v_im = (const float*)d_in[5];
    float* out = (float*)d_out;

    const size_t bf_bytes = 6 * (size_t)NELEM * 2;                 // 12 MiB staging
    const size_t mlsz     = 4 * (size_t)BS_ * 8;                   // 512 KiB
    const size_t need4f16 = bf_bytes + 4 * 2 * (size_t)NELEM * 2 + mlsz;
    const size_t need4f32 = bf_bytes + 4 * 2 * (size_t)NELEM * 4 + mlsz;

    if (ws_size >= bf_bytes) {
        short* wsb = (short*)d_ws;
        prepass_kernel<<<4608, 256, 0, stream>>>(q_re, q_im, k_re, k_im, v_re, v_im, wsb);
        char* extra = (char*)d_ws + bf_bytes;
        if (ws_size >= need4f16) {
            _Float16* opart = (_Float16*)extra;
            float* ml = (float*)(extra + 4 * 2 * (size_t)NELEM * 2);
            cv_attn_main<4, _Float16><<<B_ * 64 * 4, 256, 0, stream>>>(wsb, nullptr, opart, ml);
            cv_attn_combine<4, _Float16><<<2048, 256, 0, stream>>>(opart, ml, out);
        } else if (ws_size >= need4f32) {
            float* opart = (float*)extra;
            float* ml    = (float*)(extra + 4 * 2 * (size_t)NELEM * 4);
            cv_attn_main<4, float><<<B_ * 64 * 4, 256, 0, stream>>>(wsb, nullptr, opart, ml);
            cv_attn_combine<4, float><<<2048, 256, 0, stream>>>(opart, ml, out);
        } else {
            cv_attn_main<1, float><<<B_ * 64, 256, 0, stream>>>(wsb, out, out, nullptr);
        }
    } else {
        cv_attn_legacy<<<B_ * 64, 256, 0, stream>>>(q_re, q_im, k_re, k_im, v_re, v_im, out);
    }
}